// Round 8
// baseline (2298.748 us; speedup 1.0000x reference)
//
#include <hip/hip_runtime.h>

#define DIMF 128
#define NPB  128      // nodes per bucket (pow2 -> bucket = src>>7)
#define CAPB 2560     // max edges per bucket: mean 2048, sigma~45, +11 sigma

typedef __bf16 bf16x8 __attribute__((ext_vector_type(8)));
typedef float f32x4 __attribute__((ext_vector_type(4)));
typedef float f32x2 __attribute__((ext_vector_type(2)));

__device__ __forceinline__ unsigned short f2bf(float f) {
    union { float f; unsigned u; } v; v.f = f;
    unsigned r = v.u + 0x7FFFu + ((v.u >> 16) & 1u);
    return (unsigned short)(r >> 16);
}
__device__ __forceinline__ float bf2f(unsigned short h) {
    union { unsigned u; float f; } v; v.u = ((unsigned)h) << 16; return v.f;
}
__device__ __forceinline__ float uasf(unsigned u) {
    union { unsigned u; float f; } v; v.u = u; return v.f;
}

// ---------------- fused: zero cnt+bcur+st, convert W0 -> bf16 ----------------
__global__ __launch_bounds__(256) void k_zero_wconv(int* __restrict__ zbase, int zints,
                                                    const float* __restrict__ W, unsigned short* __restrict__ Wb,
                                                    int n4) {
    int idx = blockIdx.x * 256 + threadIdx.x;
    int z0 = idx * 2;
    if (z0 + 1 < zints) {
        *reinterpret_cast<int2*>(zbase + z0) = int2{0, 0};
    } else if (z0 < zints) {
        zbase[z0] = 0;
    }
    if (idx < n4) {
        float4 v = *reinterpret_cast<const float4*>(W + (size_t)idx * 4);
        ushort4 o = { f2bf(v.x), f2bf(v.y), f2bf(v.z), f2bf(v.w) };
        *reinterpret_cast<ushort4*>(Wb + (size_t)idx * 4) = o;
    }
}

// ---------------- stage 1: stream ea, convert bf16, append to coarse node-range buckets ----------------
// Sequential NT reads; writes go to 782 append streams -> L2 write-combining -> semi-sequential evictions.
__global__ __launch_bounds__(256) void k_scat(const float* __restrict__ ea, const int* __restrict__ src,
                                              int* __restrict__ bcur, int* __restrict__ cnt,
                                              unsigned short* __restrict__ pay, unsigned char* __restrict__ ids,
                                              int E) {
    int wv = blockIdx.x * 4 + (threadIdx.x >> 6);
    int lane = threadIdx.x & 63;
    int e0 = wv * 4;
    if (e0 >= E) return;

    // lanes 0..3: src + bucket slot + per-node count for edges e0..e0+3
    int e_l = e0 + lane;
    int sv = 0, pv = 0;
    if (lane < 4 && e_l < E) {
        sv = src[e_l];
        pv = atomicAdd(&bcur[sv >> 7], 1);
        atomicAdd(&cnt[sv], 1);
    }

    f32x2 v[4];
#pragma unroll
    for (int k = 0; k < 4; ++k) {
        int e = e0 + k;
        if (e < E)
            v[k] = __builtin_nontemporal_load(reinterpret_cast<const f32x2*>(ea + (size_t)e * DIMF) + lane);
    }
#pragma unroll
    for (int k = 0; k < 4; ++k) {
        int e = e0 + k;
        if (e < E) {
            int s = __shfl(sv, k, 64);
            int p = __shfl(pv, k, 64);
            if (p < CAPB) {
                size_t slot = (size_t)(s >> 7) * CAPB + p;
                ushort2 o = { f2bf(v[k][0]), f2bf(v[k][1]) };
                *(reinterpret_cast<ushort2*>(pay + slot * DIMF) + lane) = o;   // cached store: L2 combines
                if (lane == 0) ids[slot] = (unsigned char)(s & (NPB - 1));
            }
        }
    }
}

// ---------------- stage 2: per-bucket sequential read + LDS f32 accumulate + mean -> ve bf16 ----------------
__global__ __launch_bounds__(256) void k_scat2(const unsigned short* __restrict__ pay,
                                               const unsigned char* __restrict__ ids,
                                               const int* __restrict__ bcur, const int* __restrict__ cnt,
                                               unsigned short* __restrict__ ve, int n) {
    extern __shared__ float acc[];   // NPB*128 f32 = 64 KB
    int tid = threadIdx.x;
    for (int i = tid; i < NPB * DIMF; i += 256) acc[i] = 0.f;
    __syncthreads();

    int b = blockIdx.x;
    size_t base = (size_t)b * CAPB;
    int m = bcur[b]; if (m > CAPB) m = CAPB;
    int wave = tid >> 6, lane = tid & 63;

    for (int i = wave; i < m; i += 4) {
        unsigned w = *(reinterpret_cast<const unsigned*>(pay + (base + i) * DIMF) + lane);  // 256B/row coalesced
        int j = ids[base + i];                                                              // broadcast load
        atomicAdd(&acc[j * DIMF + lane * 2],     uasf(w << 16));
        atomicAdd(&acc[j * DIMF + lane * 2 + 1], uasf(w & 0xffff0000u));
    }
    __syncthreads();

    // write out: 128 rows x 16 chunks of 8 cols = 2048 chunks, 8 per thread
    int node0 = b * NPB;
#pragma unroll
    for (int it = 0; it < 8; ++it) {
        int q = tid + it * 256;
        int j = q >> 4, c8 = (q & 15) * 8;
        int node = node0 + j;
        if (node < n) {
            int c = cnt[node];
            float inv = 1.0f / (float)(c > 1 ? c : 1);
            const float* ap = &acc[j * DIMF + c8];
            ushort4 o0 = { f2bf(ap[0] * inv), f2bf(ap[1] * inv), f2bf(ap[2] * inv), f2bf(ap[3] * inv) };
            ushort4 o1 = { f2bf(ap[4] * inv), f2bf(ap[5] * inv), f2bf(ap[6] * inv), f2bf(ap[7] * inv) };
            *reinterpret_cast<ushort4*>(ve + (size_t)node * DIMF + c8) = o0;
            *reinterpret_cast<ushort4*>(ve + (size_t)node * DIMF + c8 + 4) = o1;
        }
    }
}

#define BM 64

// ---------------- GEMM layer 0: 3 K-chunks (x | ve | u[batch]), A+B staged in LDS ----------------
__global__ __launch_bounds__(256) void k_gemm0(const float* __restrict__ x,
                                               const unsigned short* __restrict__ ve,
                                               const float* __restrict__ u,
                                               const int* __restrict__ batch,
                                               const unsigned short* __restrict__ W,   // [128][384] bf16
                                               const float* __restrict__ bias,
                                               unsigned short* __restrict__ H,
                                               float* __restrict__ st, int rows) {
    __shared__ __align__(16) unsigned short lA[BM][136];
    __shared__ __align__(16) unsigned short lB[DIMF][136];
    __shared__ float sm[DIMF], sq[DIMF];
    __shared__ int sbatch[BM];
    int tid = threadIdx.x;
    int row0 = blockIdx.x * BM;
    if (tid < DIMF) { sm[tid] = 0.f; sq[tid] = 0.f; }
    if (tid < BM) {
        int gr = row0 + tid;
        sbatch[tid] = (gr < rows) ? batch[gr] : 0;
    }

    int lane = tid & 63, wave = tid >> 6;
    int wm = wave >> 1, wn = wave & 1;
    int l15 = lane & 15, l4 = lane >> 4;
    f32x4 acc[2][4] = {};

    int fr = tid >> 5, fc = (tid & 31) * 4;   // f32 source map
    int hr = tid >> 4, hc = (tid & 15) * 8;   // bf16 source map

#pragma unroll
    for (int chunk = 0; chunk < 3; ++chunk) {
        if (chunk == 0) {
#pragma unroll
            for (int i = 0; i < 8; ++i) {
                int r = fr + i * 8;
                int gr = row0 + r;
                float4 v = (gr < rows) ? *reinterpret_cast<const float4*>(x + (size_t)gr * DIMF + fc)
                                       : float4{0.f, 0.f, 0.f, 0.f};
                ushort4 o2 = { f2bf(v.x), f2bf(v.y), f2bf(v.z), f2bf(v.w) };
                *reinterpret_cast<ushort4*>(&lA[r][fc]) = o2;
            }
        } else if (chunk == 1) {
#pragma unroll
            for (int i = 0; i < 4; ++i) {
                int r = hr + i * 16;
                int gr = row0 + r;
                uint4 v = (gr < rows) ? *reinterpret_cast<const uint4*>(ve + (size_t)gr * DIMF + hc)
                                      : uint4{0u, 0u, 0u, 0u};
                *reinterpret_cast<uint4*>(&lA[r][hc]) = v;
            }
        } else {
#pragma unroll
            for (int i = 0; i < 8; ++i) {
                int r = fr + i * 8;
                int gr = row0 + r;
                int b = sbatch[r];
                float4 v = (gr < rows) ? *reinterpret_cast<const float4*>(u + (size_t)b * DIMF + fc)
                                       : float4{0.f, 0.f, 0.f, 0.f};
                ushort4 o2 = { f2bf(v.x), f2bf(v.y), f2bf(v.z), f2bf(v.w) };
                *reinterpret_cast<ushort4*>(&lA[r][fc]) = o2;
            }
        }
#pragma unroll
        for (int i = 0; i < 8; ++i) {
            int r = hr + i * 16;
            uint4 v = *reinterpret_cast<const uint4*>(W + (size_t)r * 384 + chunk * 128 + hc);
            *reinterpret_cast<uint4*>(&lB[r][hc]) = v;
        }
        __syncthreads();
#pragma unroll
        for (int ks = 0; ks < 4; ++ks) {
            bf16x8 af[2], bfr[4];
#pragma unroll
            for (int mi = 0; mi < 2; ++mi)
                af[mi] = *reinterpret_cast<const bf16x8*>(&lA[wm * 32 + mi * 16 + l15][ks * 32 + l4 * 8]);
#pragma unroll
            for (int ni = 0; ni < 4; ++ni)
                bfr[ni] = *reinterpret_cast<const bf16x8*>(&lB[wn * 64 + ni * 16 + l15][ks * 32 + l4 * 8]);
#pragma unroll
            for (int mi = 0; mi < 2; ++mi)
#pragma unroll
                for (int ni = 0; ni < 4; ++ni)
                    acc[mi][ni] = __builtin_amdgcn_mfma_f32_16x16x32_bf16(af[mi], bfr[ni], acc[mi][ni], 0, 0, 0);
        }
        __syncthreads();
    }

#pragma unroll
    for (int mi = 0; mi < 2; ++mi)
#pragma unroll
        for (int ni = 0; ni < 4; ++ni) {
            int c = wn * 64 + ni * 16 + l15;
            float s = 0.f, q = 0.f;
#pragma unroll
            for (int i = 0; i < 4; ++i) {
                int r = row0 + wm * 32 + mi * 16 + l4 * 4 + i;
                if (r < rows) {
                    float z = acc[mi][ni][i] + bias[c];
                    z = fmaxf(z, 0.f);
                    H[(size_t)r * DIMF + c] = f2bf(z);
                    s += z; q += z * z;
                }
            }
            atomicAdd(&sm[c], s);
            atomicAdd(&sq[c], q);
        }
    __syncthreads();
    if (tid < DIMF) { atomicAdd(&st[tid], sm[tid]); atomicAdd(&st[DIMF + tid], sq[tid]); }
}

// ---------------- GEMM layers 1,2 with in-kernel BN fold ----------------
__global__ __launch_bounds__(256) void k_gemmF(const unsigned short* __restrict__ A,
                                               const float* __restrict__ W,     // [128][128] fp32 (raw)
                                               const float* __restrict__ bn,    // raw bias
                                               const float* __restrict__ stp,   // prev-layer stats
                                               const float* __restrict__ g,
                                               const float* __restrict__ bt,
                                               unsigned short* __restrict__ H,
                                               float* __restrict__ st, int rows) {
    const int K = 128;
    __shared__ __align__(16) unsigned short lA[BM][136];
    __shared__ __align__(16) unsigned short lB[DIMF][136];
    __shared__ float sS[DIMF], sT[DIMF], bb[DIMF], sm[DIMF], sq[DIMF];
    int tid = threadIdx.x;
    int row0 = blockIdx.x * BM;

    if (tid < DIMF) {
        float invn = 1.0f / (float)rows;
        float mu = stp[tid] * invn;
        float var = stp[DIMF + tid] * invn - mu * mu;
        var = var > 0.f ? var : 0.f;
        float sc = rsqrtf(var + 1e-5f) * g[tid];
        sS[tid] = sc;
        sT[tid] = bt[tid] - mu * sc;
        sm[tid] = 0.f; sq[tid] = 0.f;
    }

    int hr = tid >> 4, hc = (tid & 15) * 8;
#pragma unroll
    for (int i = 0; i < 4; ++i) {
        int r = hr + i * 16;
        int gr = row0 + r;
        uint4 v = (gr < rows) ? *reinterpret_cast<const uint4*>(A + (size_t)gr * K + hc)
                              : uint4{0u, 0u, 0u, 0u};
        *reinterpret_cast<uint4*>(&lA[r][hc]) = v;
    }
    __syncthreads();   // sS/sT ready, lA ready

    int fr = tid >> 5, fc = (tid & 31) * 4;
#pragma unroll
    for (int it = 0; it < 16; ++it) {
        int r = fr + it * 8;
        float4 w = *reinterpret_cast<const float4*>(W + (size_t)r * K + fc);
        ushort4 ob = { f2bf(w.x * sS[fc]), f2bf(w.y * sS[fc + 1]),
                       f2bf(w.z * sS[fc + 2]), f2bf(w.w * sS[fc + 3]) };
        *reinterpret_cast<ushort4*>(&lB[r][fc]) = ob;
        float p = w.x * sT[fc] + w.y * sT[fc + 1] + w.z * sT[fc + 2] + w.w * sT[fc + 3];
#pragma unroll
        for (int m = 16; m > 0; m >>= 1) p += __shfl_xor(p, m, 32);
        if ((tid & 31) == 0) bb[r] = bn[r] + p;
    }
    __syncthreads();

    int lane = tid & 63, wave = tid >> 6;
    int wm = wave >> 1, wn = wave & 1;
    int l15 = lane & 15, l4 = lane >> 4;
    f32x4 acc[2][4] = {};

#pragma unroll
    for (int ks = 0; ks < 4; ++ks) {
        bf16x8 af[2], bfr[4];
#pragma unroll
        for (int mi = 0; mi < 2; ++mi)
            af[mi] = *reinterpret_cast<const bf16x8*>(&lA[wm * 32 + mi * 16 + l15][ks * 32 + l4 * 8]);
#pragma unroll
        for (int ni = 0; ni < 4; ++ni)
            bfr[ni] = *reinterpret_cast<const bf16x8*>(&lB[wn * 64 + ni * 16 + l15][ks * 32 + l4 * 8]);
#pragma unroll
        for (int mi = 0; mi < 2; ++mi)
#pragma unroll
            for (int ni = 0; ni < 4; ++ni)
                acc[mi][ni] = __builtin_amdgcn_mfma_f32_16x16x32_bf16(af[mi], bfr[ni], acc[mi][ni], 0, 0, 0);
    }

#pragma unroll
    for (int mi = 0; mi < 2; ++mi)
#pragma unroll
        for (int ni = 0; ni < 4; ++ni) {
            int c = wn * 64 + ni * 16 + l15;
            float s = 0.f, q = 0.f;
#pragma unroll
            for (int i = 0; i < 4; ++i) {
                int r = row0 + wm * 32 + mi * 16 + l4 * 4 + i;
                if (r < rows) {
                    float z = acc[mi][ni][i] + bb[c];
                    z = fmaxf(z, 0.f);
                    H[(size_t)r * DIMF + c] = f2bf(z);
                    s += z; q += z * z;
                }
            }
            atomicAdd(&sm[c], s);
            atomicAdd(&sq[c], q);
        }
    __syncthreads();
    if (tid < DIMF) { atomicAdd(&st[tid], sm[tid]); atomicAdd(&st[DIMF + tid], sq[tid]); }
}

// final: out = h2 * s + t, BN params computed inline from st
__global__ __launch_bounds__(256) void k_final(const unsigned short* __restrict__ H, const float* __restrict__ st,
                                               const float* __restrict__ g, const float* __restrict__ bt,
                                               float* __restrict__ out, int n) {
    int idx = blockIdx.x * 256 + threadIdx.x;
    if (idx >= n * 32) return;
    int r = idx >> 5, q = (idx & 31) * 4;
    float invn = 1.0f / (float)n;
    ushort4 h = *reinterpret_cast<const ushort4*>(H + (size_t)r * DIMF + q);
    float hv[4] = { bf2f(h.x), bf2f(h.y), bf2f(h.z), bf2f(h.w) };
    float ov[4];
#pragma unroll
    for (int k = 0; k < 4; ++k) {
        int c = q + k;
        float mu = st[c] * invn;
        float var = st[DIMF + c] * invn - mu * mu;
        var = var > 0.f ? var : 0.f;
        float sc = rsqrtf(var + 1e-5f) * g[c];
        ov[k] = hv[k] * sc + (bt[c] - mu * sc);
    }
    float4 o = { ov[0], ov[1], ov[2], ov[3] };
    *reinterpret_cast<float4*>(out + (size_t)r * DIMF + q) = o;
}

extern "C" void kernel_launch(void* const* d_in, const int* in_sizes, int n_in,
                              void* d_out, int out_size, void* d_ws, size_t ws_size,
                              hipStream_t stream) {
    const float* x   = (const float*)d_in[0];
    const float* ea  = (const float*)d_in[1];
    const float* u   = (const float*)d_in[2];
    const int* eidx  = (const int*)d_in[3];
    const int* batch = (const int*)d_in[4];
    const float* W0  = (const float*)d_in[5];
    const float* b0  = (const float*)d_in[6];
    const float* W1  = (const float*)d_in[7];
    const float* b1  = (const float*)d_in[8];
    const float* W2  = (const float*)d_in[9];
    const float* b2  = (const float*)d_in[10];
    const float* g0  = (const float*)d_in[11];
    const float* bt0 = (const float*)d_in[12];
    const float* g1  = (const float*)d_in[13];
    const float* bt1 = (const float*)d_in[14];
    const float* g2  = (const float*)d_in[15];
    const float* bt2 = (const float*)d_in[16];

    int N = in_sizes[0] / DIMF;
    int E = in_sizes[1] / DIMF;
    const int* src = eidx;  // row 0 of edge_index
    int NBK = (N + NPB - 1) / NPB;   // number of buckets (782 for N=100K)

    char* base = (char*)d_ws;
    size_t o = 0;
    auto alloc = [&](size_t sz) { size_t p = o; o = (o + sz + 255) & ~(size_t)255; return p; };
    size_t off_cnt   = alloc((size_t)N * 4);          // zeroed
    size_t off_bcur  = alloc((size_t)NBK * 4);        // zeroed (contiguous)
    size_t off_st    = alloc(3 * 256 * 4);            // zeroed (contiguous)
    size_t off_W0b   = alloc((size_t)DIMF * 384 * 2);
    size_t off_ve    = alloc((size_t)N * DIMF * 2);
    size_t off_h0    = alloc((size_t)N * DIMF * 2);
    size_t off_h1    = alloc((size_t)N * DIMF * 2);
    size_t off_h2    = alloc((size_t)N * DIMF * 2);
    size_t off_ids   = alloc((size_t)NBK * CAPB);
    size_t off_pay   = alloc((size_t)NBK * CAPB * DIMF * 2);   // ~513 MB

    int* cnt        = (int*)(base + off_cnt);
    int* bcur       = (int*)(base + off_bcur);
    float* st       = (float*)(base + off_st);
    unsigned short* W0b = (unsigned short*)(base + off_W0b);
    unsigned short* ve  = (unsigned short*)(base + off_ve);
    unsigned short* h0  = (unsigned short*)(base + off_h0);
    unsigned short* h1  = (unsigned short*)(base + off_h1);
    unsigned short* h2  = (unsigned short*)(base + off_h2);
    unsigned char* ids  = (unsigned char*)(base + off_ids);
    unsigned short* pay = (unsigned short*)(base + off_pay);
    float* outp = (float*)d_out;

    int zints = (int)((off_st + 3 * 256 * 4) / 4);   // cnt + bcur + st contiguous zero region
    int NQ = (N * 32 + 255) / 256;
    int GB = (N + BM - 1) / BM;
    int SB = (E + 15) / 16;

    k_zero_wconv<<<256, 256, 0, stream>>>((int*)base, zints, W0, W0b, DIMF * 384 / 4);
    k_scat<<<SB, 256, 0, stream>>>(ea, src, bcur, cnt, pay, ids, E);
    k_scat2<<<NBK, 256, NPB * DIMF * 4, stream>>>(pay, ids, bcur, cnt, ve, N);

    // layer 0 (stats fused)
    k_gemm0<<<GB, 256, 0, stream>>>(x, ve, u, batch, W0b, b0, h0, st, N);
    // layer 1 (BN0 folded in-kernel, stats fused)
    k_gemmF<<<GB, 256, 0, stream>>>(h0, W1, b1, st, g0, bt0, h1, st + 256, N);
    // layer 2 (BN1 folded in-kernel, stats fused)
    k_gemmF<<<GB, 256, 0, stream>>>(h1, W2, b2, st + 256, g1, bt1, h2, st + 512, N);
    // final BN2
    k_final<<<NQ, 256, 0, stream>>>(h2, st + 512, g2, bt2, outp, N);
}

// Round 9
// 1669.205 us; speedup vs baseline: 1.3772x; 1.3772x over previous
//
#include <hip/hip_runtime.h>

#define DIMF 128

typedef __bf16 bf16x8 __attribute__((ext_vector_type(8)));
typedef float f32x4 __attribute__((ext_vector_type(4)));
typedef float f32x2 __attribute__((ext_vector_type(2)));

__device__ __forceinline__ unsigned short f2bf(float f) {
    union { float f; unsigned u; } v; v.f = f;
    unsigned r = v.u + 0x7FFFu + ((v.u >> 16) & 1u);
    return (unsigned short)(r >> 16);
}
__device__ __forceinline__ float bf2f(unsigned short h) {
    union { unsigned u; float f; } v; v.u = ((unsigned)h) << 16; return v.f;
}

// ---------------- fused: zero cnt+st, convert W0 -> bf16 ----------------
__global__ __launch_bounds__(256) void k_zero_wconv(int* __restrict__ zbase, int zints,
                                                    const float* __restrict__ W, unsigned short* __restrict__ Wb,
                                                    int n4) {
    int idx = blockIdx.x * 256 + threadIdx.x;
    int z0 = idx * 2;
    if (z0 + 1 < zints) {
        *reinterpret_cast<int2*>(zbase + z0) = int2{0, 0};
    } else if (z0 < zints) {
        zbase[z0] = 0;
    }
    if (idx < n4) {
        float4 v = *reinterpret_cast<const float4*>(W + (size_t)idx * 4);
        ushort4 o = { f2bf(v.x), f2bf(v.y), f2bf(v.z), f2bf(v.w) };
        *reinterpret_cast<ushort4*>(Wb + (size_t)idx * 4) = o;
    }
}

// ---------------- edge scatter: sequential ea stream -> f32 atomics into L2/LLC-resident vsum ----------------
// One wave per 4 consecutive edges (2KB sequential NT read burst), then 8 posted
// atomic f32 adds per lane-pair into vsum[src][:]. vsum (51.2MB) fits in IF$;
// random side never touches DRAM.
__global__ __launch_bounds__(256) void k_edge(const float* __restrict__ ea, const int* __restrict__ src,
                                              float* __restrict__ vsum, int* __restrict__ cnt, int E) {
    int nw = gridDim.x * 4;
    int wv = blockIdx.x * 4 + (threadIdx.x >> 6);
    int lane = threadIdx.x & 63;
    for (int e0 = wv * 4; e0 < E; e0 += nw * 4) {
        f32x2 v[4]; int s[4];
#pragma unroll
        for (int k = 0; k < 4; ++k) {
            int e = e0 + k;
            if (e < E) {
                v[k] = __builtin_nontemporal_load(reinterpret_cast<const f32x2*>(ea + (size_t)e * DIMF) + lane);
                s[k] = src[e];
            }
        }
#pragma unroll
        for (int k = 0; k < 4; ++k) {
            int e = e0 + k;
            if (e < E) {
                float* dst = vsum + (size_t)s[k] * DIMF + lane * 2;
                atomicAdd(dst, v[k][0]);
                atomicAdd(dst + 1, v[k][1]);
                if (lane == 0) atomicAdd(&cnt[s[k]], 1);
            }
        }
    }
}

// ---------------- vsum/cnt -> ve bf16 ----------------
__global__ __launch_bounds__(256) void k_ve(const float* __restrict__ vsum, const int* __restrict__ cnt,
                                            unsigned short* __restrict__ ve, int n) {
    int idx = blockIdx.x * 256 + threadIdx.x;
    if (idx >= n * 32) return;
    int r = idx >> 5, q = (idx & 31) * 4;
    int c = cnt[r];
    float inv = 1.0f / (float)(c > 1 ? c : 1);
    float4 v = *reinterpret_cast<const float4*>(vsum + (size_t)r * DIMF + q);
    ushort4 o = { f2bf(v.x * inv), f2bf(v.y * inv), f2bf(v.z * inv), f2bf(v.w * inv) };
    *reinterpret_cast<ushort4*>(ve + (size_t)r * DIMF + q) = o;
}

#define BM 64

// ---------------- GEMM layer 0: 3 K-chunks (x | ve | u[batch]), A+B staged in LDS ----------------
__global__ __launch_bounds__(256) void k_gemm0(const float* __restrict__ x,
                                               const unsigned short* __restrict__ ve,
                                               const float* __restrict__ u,
                                               const int* __restrict__ batch,
                                               const unsigned short* __restrict__ W,   // [128][384] bf16
                                               const float* __restrict__ bias,
                                               unsigned short* __restrict__ H,
                                               float* __restrict__ st, int rows) {
    __shared__ __align__(16) unsigned short lA[BM][136];
    __shared__ __align__(16) unsigned short lB[DIMF][136];
    __shared__ float sm[DIMF], sq[DIMF];
    __shared__ int sbatch[BM];
    int tid = threadIdx.x;
    int row0 = blockIdx.x * BM;
    if (tid < DIMF) { sm[tid] = 0.f; sq[tid] = 0.f; }
    if (tid < BM) {
        int gr = row0 + tid;
        sbatch[tid] = (gr < rows) ? batch[gr] : 0;
    }

    int lane = tid & 63, wave = tid >> 6;
    int wm = wave >> 1, wn = wave & 1;
    int l15 = lane & 15, l4 = lane >> 4;
    f32x4 acc[2][4] = {};

    int fr = tid >> 5, fc = (tid & 31) * 4;   // f32 source map
    int hr = tid >> 4, hc = (tid & 15) * 8;   // bf16 source map

#pragma unroll
    for (int chunk = 0; chunk < 3; ++chunk) {
        if (chunk == 0) {
#pragma unroll
            for (int i = 0; i < 8; ++i) {
                int r = fr + i * 8;
                int gr = row0 + r;
                float4 v = (gr < rows) ? *reinterpret_cast<const float4*>(x + (size_t)gr * DIMF + fc)
                                       : float4{0.f, 0.f, 0.f, 0.f};
                ushort4 o2 = { f2bf(v.x), f2bf(v.y), f2bf(v.z), f2bf(v.w) };
                *reinterpret_cast<ushort4*>(&lA[r][fc]) = o2;
            }
        } else if (chunk == 1) {
#pragma unroll
            for (int i = 0; i < 4; ++i) {
                int r = hr + i * 16;
                int gr = row0 + r;
                uint4 v = (gr < rows) ? *reinterpret_cast<const uint4*>(ve + (size_t)gr * DIMF + hc)
                                      : uint4{0u, 0u, 0u, 0u};
                *reinterpret_cast<uint4*>(&lA[r][hc]) = v;
            }
        } else {
#pragma unroll
            for (int i = 0; i < 8; ++i) {
                int r = fr + i * 8;
                int gr = row0 + r;
                int b = sbatch[r];
                float4 v = (gr < rows) ? *reinterpret_cast<const float4*>(u + (size_t)b * DIMF + fc)
                                       : float4{0.f, 0.f, 0.f, 0.f};
                ushort4 o2 = { f2bf(v.x), f2bf(v.y), f2bf(v.z), f2bf(v.w) };
                *reinterpret_cast<ushort4*>(&lA[r][fc]) = o2;
            }
        }
#pragma unroll
        for (int i = 0; i < 8; ++i) {
            int r = hr + i * 16;
            uint4 v = *reinterpret_cast<const uint4*>(W + (size_t)r * 384 + chunk * 128 + hc);
            *reinterpret_cast<uint4*>(&lB[r][hc]) = v;
        }
        __syncthreads();
#pragma unroll
        for (int ks = 0; ks < 4; ++ks) {
            bf16x8 af[2], bfr[4];
#pragma unroll
            for (int mi = 0; mi < 2; ++mi)
                af[mi] = *reinterpret_cast<const bf16x8*>(&lA[wm * 32 + mi * 16 + l15][ks * 32 + l4 * 8]);
#pragma unroll
            for (int ni = 0; ni < 4; ++ni)
                bfr[ni] = *reinterpret_cast<const bf16x8*>(&lB[wn * 64 + ni * 16 + l15][ks * 32 + l4 * 8]);
#pragma unroll
            for (int mi = 0; mi < 2; ++mi)
#pragma unroll
                for (int ni = 0; ni < 4; ++ni)
                    acc[mi][ni] = __builtin_amdgcn_mfma_f32_16x16x32_bf16(af[mi], bfr[ni], acc[mi][ni], 0, 0, 0);
        }
        __syncthreads();
    }

#pragma unroll
    for (int mi = 0; mi < 2; ++mi)
#pragma unroll
        for (int ni = 0; ni < 4; ++ni) {
            int c = wn * 64 + ni * 16 + l15;
            float s = 0.f, q = 0.f;
#pragma unroll
            for (int i = 0; i < 4; ++i) {
                int r = row0 + wm * 32 + mi * 16 + l4 * 4 + i;
                if (r < rows) {
                    float z = acc[mi][ni][i] + bias[c];
                    z = fmaxf(z, 0.f);
                    H[(size_t)r * DIMF + c] = f2bf(z);
                    s += z; q += z * z;
                }
            }
            atomicAdd(&sm[c], s);
            atomicAdd(&sq[c], q);
        }
    __syncthreads();
    if (tid < DIMF) { atomicAdd(&st[tid], sm[tid]); atomicAdd(&st[DIMF + tid], sq[tid]); }
}

// ---------------- GEMM layers 1,2 with in-kernel BN fold ----------------
__global__ __launch_bounds__(256) void k_gemmF(const unsigned short* __restrict__ A,
                                               const float* __restrict__ W,     // [128][128] fp32 (raw)
                                               const float* __restrict__ bn,    // raw bias
                                               const float* __restrict__ stp,   // prev-layer stats
                                               const float* __restrict__ g,
                                               const float* __restrict__ bt,
                                               unsigned short* __restrict__ H,
                                               float* __restrict__ st, int rows) {
    const int K = 128;
    __shared__ __align__(16) unsigned short lA[BM][136];
    __shared__ __align__(16) unsigned short lB[DIMF][136];
    __shared__ float sS[DIMF], sT[DIMF], bb[DIMF], sm[DIMF], sq[DIMF];
    int tid = threadIdx.x;
    int row0 = blockIdx.x * BM;

    if (tid < DIMF) {
        float invn = 1.0f / (float)rows;
        float mu = stp[tid] * invn;
        float var = stp[DIMF + tid] * invn - mu * mu;
        var = var > 0.f ? var : 0.f;
        float sc = rsqrtf(var + 1e-5f) * g[tid];
        sS[tid] = sc;
        sT[tid] = bt[tid] - mu * sc;
        sm[tid] = 0.f; sq[tid] = 0.f;
    }

    int hr = tid >> 4, hc = (tid & 15) * 8;
#pragma unroll
    for (int i = 0; i < 4; ++i) {
        int r = hr + i * 16;
        int gr = row0 + r;
        uint4 v = (gr < rows) ? *reinterpret_cast<const uint4*>(A + (size_t)gr * K + hc)
                              : uint4{0u, 0u, 0u, 0u};
        *reinterpret_cast<uint4*>(&lA[r][hc]) = v;
    }
    __syncthreads();   // sS/sT ready, lA ready

    int fr = tid >> 5, fc = (tid & 31) * 4;
#pragma unroll
    for (int it = 0; it < 16; ++it) {
        int r = fr + it * 8;
        float4 w = *reinterpret_cast<const float4*>(W + (size_t)r * K + fc);
        ushort4 ob = { f2bf(w.x * sS[fc]), f2bf(w.y * sS[fc + 1]),
                       f2bf(w.z * sS[fc + 2]), f2bf(w.w * sS[fc + 3]) };
        *reinterpret_cast<ushort4*>(&lB[r][fc]) = ob;
        float p = w.x * sT[fc] + w.y * sT[fc + 1] + w.z * sT[fc + 2] + w.w * sT[fc + 3];
#pragma unroll
        for (int m = 16; m > 0; m >>= 1) p += __shfl_xor(p, m, 32);
        if ((tid & 31) == 0) bb[r] = bn[r] + p;
    }
    __syncthreads();

    int lane = tid & 63, wave = tid >> 6;
    int wm = wave >> 1, wn = wave & 1;
    int l15 = lane & 15, l4 = lane >> 4;
    f32x4 acc[2][4] = {};

#pragma unroll
    for (int ks = 0; ks < 4; ++ks) {
        bf16x8 af[2], bfr[4];
#pragma unroll
        for (int mi = 0; mi < 2; ++mi)
            af[mi] = *reinterpret_cast<const bf16x8*>(&lA[wm * 32 + mi * 16 + l15][ks * 32 + l4 * 8]);
#pragma unroll
        for (int ni = 0; ni < 4; ++ni)
            bfr[ni] = *reinterpret_cast<const bf16x8*>(&lB[wn * 64 + ni * 16 + l15][ks * 32 + l4 * 8]);
#pragma unroll
        for (int mi = 0; mi < 2; ++mi)
#pragma unroll
            for (int ni = 0; ni < 4; ++ni)
                acc[mi][ni] = __builtin_amdgcn_mfma_f32_16x16x32_bf16(af[mi], bfr[ni], acc[mi][ni], 0, 0, 0);
    }

#pragma unroll
    for (int mi = 0; mi < 2; ++mi)
#pragma unroll
        for (int ni = 0; ni < 4; ++ni) {
            int c = wn * 64 + ni * 16 + l15;
            float s = 0.f, q = 0.f;
#pragma unroll
            for (int i = 0; i < 4; ++i) {
                int r = row0 + wm * 32 + mi * 16 + l4 * 4 + i;
                if (r < rows) {
                    float z = acc[mi][ni][i] + bb[c];
                    z = fmaxf(z, 0.f);
                    H[(size_t)r * DIMF + c] = f2bf(z);
                    s += z; q += z * z;
                }
            }
            atomicAdd(&sm[c], s);
            atomicAdd(&sq[c], q);
        }
    __syncthreads();
    if (tid < DIMF) { atomicAdd(&st[tid], sm[tid]); atomicAdd(&st[DIMF + tid], sq[tid]); }
}

// final: out = h2 * s + t, BN params computed inline from st
__global__ __launch_bounds__(256) void k_final(const unsigned short* __restrict__ H, const float* __restrict__ st,
                                               const float* __restrict__ g, const float* __restrict__ bt,
                                               float* __restrict__ out, int n) {
    int idx = blockIdx.x * 256 + threadIdx.x;
    if (idx >= n * 32) return;
    int r = idx >> 5, q = (idx & 31) * 4;
    float invn = 1.0f / (float)n;
    ushort4 h = *reinterpret_cast<const ushort4*>(H + (size_t)r * DIMF + q);
    float hv[4] = { bf2f(h.x), bf2f(h.y), bf2f(h.z), bf2f(h.w) };
    float ov[4];
#pragma unroll
    for (int k = 0; k < 4; ++k) {
        int c = q + k;
        float mu = st[c] * invn;
        float var = st[DIMF + c] * invn - mu * mu;
        var = var > 0.f ? var : 0.f;
        float sc = rsqrtf(var + 1e-5f) * g[c];
        ov[k] = hv[k] * sc + (bt[c] - mu * sc);
    }
    float4 o = { ov[0], ov[1], ov[2], ov[3] };
    *reinterpret_cast<float4*>(out + (size_t)r * DIMF + q) = o;
}

extern "C" void kernel_launch(void* const* d_in, const int* in_sizes, int n_in,
                              void* d_out, int out_size, void* d_ws, size_t ws_size,
                              hipStream_t stream) {
    const float* x   = (const float*)d_in[0];
    const float* ea  = (const float*)d_in[1];
    const float* u   = (const float*)d_in[2];
    const int* eidx  = (const int*)d_in[3];
    const int* batch = (const int*)d_in[4];
    const float* W0  = (const float*)d_in[5];
    const float* b0  = (const float*)d_in[6];
    const float* W1  = (const float*)d_in[7];
    const float* b1  = (const float*)d_in[8];
    const float* W2  = (const float*)d_in[9];
    const float* b2  = (const float*)d_in[10];
    const float* g0  = (const float*)d_in[11];
    const float* bt0 = (const float*)d_in[12];
    const float* g1  = (const float*)d_in[13];
    const float* bt1 = (const float*)d_in[14];
    const float* g2  = (const float*)d_in[15];
    const float* bt2 = (const float*)d_in[16];

    int N = in_sizes[0] / DIMF;
    int E = in_sizes[1] / DIMF;
    const int* src = eidx;  // row 0 of edge_index

    char* base = (char*)d_ws;
    size_t o = 0;
    auto alloc = [&](size_t sz) { size_t p = o; o = (o + sz + 255) & ~(size_t)255; return p; };
    size_t off_cnt   = alloc((size_t)N * 4);          // zeroed by k_zero_wconv
    size_t off_st    = alloc(3 * 256 * 4);            // zeroed (contiguous with cnt)
    size_t off_W0b   = alloc((size_t)DIMF * 384 * 2);
    size_t off_ve    = alloc((size_t)N * DIMF * 2);
    size_t off_h0    = alloc((size_t)N * DIMF * 2);
    size_t off_h1    = alloc((size_t)N * DIMF * 2);
    size_t off_h2    = alloc((size_t)N * DIMF * 2);
    size_t off_vsum  = alloc((size_t)N * DIMF * 4);   // 51.2 MB -> IF$-resident

    int* cnt        = (int*)(base + off_cnt);
    float* st       = (float*)(base + off_st);
    unsigned short* W0b = (unsigned short*)(base + off_W0b);
    unsigned short* ve  = (unsigned short*)(base + off_ve);
    unsigned short* h0  = (unsigned short*)(base + off_h0);
    unsigned short* h1  = (unsigned short*)(base + off_h1);
    unsigned short* h2  = (unsigned short*)(base + off_h2);
    float* vsum     = (float*)(base + off_vsum);
    float* outp = (float*)d_out;

    int zints = (int)((off_st + 3 * 256 * 4) / 4);   // cnt + st contiguous zero region
    int NQ = (N * 32 + 255) / 256;
    int GB = (N + BM - 1) / BM;

    k_zero_wconv<<<256, 256, 0, stream>>>((int*)base, zints, W0, W0b, DIMF * 384 / 4);
    hipMemsetAsync(vsum, 0, (size_t)N * DIMF * 4, stream);

    k_edge<<<4096, 256, 0, stream>>>(ea, src, vsum, cnt, E);
    k_ve<<<NQ, 256, 0, stream>>>(vsum, cnt, ve, N);

    // layer 0 (stats fused)
    k_gemm0<<<GB, 256, 0, stream>>>(x, ve, u, batch, W0b, b0, h0, st, N);
    // layer 1 (BN0 folded in-kernel, stats fused)
    k_gemmF<<<GB, 256, 0, stream>>>(h0, W1, b1, st, g0, bt0, h1, st + 256, N);
    // layer 2 (BN1 folded in-kernel, stats fused)
    k_gemmF<<<GB, 256, 0, stream>>>(h1, W2, b2, st + 256, g1, bt1, h2, st + 512, N);
    // final BN2
    k_final<<<NQ, 256, 0, stream>>>(h2, st + 512, g2, bt2, outp, N);
}

// Round 10
// 531.498 us; speedup vs baseline: 4.3250x; 3.1406x over previous
//
#include <hip/hip_runtime.h>

#define DIMF 128
#define CAP 128   // max edges per node bucket (deg ~ Poisson(16), max ~45 over 100K nodes)

typedef __bf16 bf16x8 __attribute__((ext_vector_type(8)));
typedef float f32x4 __attribute__((ext_vector_type(4)));
typedef float f32x2 __attribute__((ext_vector_type(2)));

__device__ __forceinline__ unsigned short f2bf(float f) {
    union { float f; unsigned u; } v; v.f = f;
    unsigned r = v.u + 0x7FFFu + ((v.u >> 16) & 1u);
    return (unsigned short)(r >> 16);
}
__device__ __forceinline__ float bf2f(unsigned short h) {
    union { unsigned u; float f; } v; v.u = ((unsigned)h) << 16; return v.f;
}

// ---------------- fused: zero cnt+st, convert W0 -> bf16 ----------------
__global__ __launch_bounds__(256) void k_zero_wconv(int* __restrict__ zbase, int zints,
                                                    const float* __restrict__ W, unsigned short* __restrict__ Wb,
                                                    int n4) {
    int idx = blockIdx.x * 256 + threadIdx.x;
    int z0 = idx * 2;
    if (z0 + 1 < zints) {
        *reinterpret_cast<int2*>(zbase + z0) = int2{0, 0};
    } else if (z0 < zints) {
        zbase[z0] = 0;
    }
    if (idx < n4) {
        float4 v = *reinterpret_cast<const float4*>(W + (size_t)idx * 4);
        ushort4 o = { f2bf(v.x), f2bf(v.y), f2bf(v.z), f2bf(v.w) };
        *reinterpret_cast<ushort4*>(Wb + (size_t)idx * 4) = o;
    }
}

// ---------------- single-pass bucketed edge binning ----------------
__global__ __launch_bounds__(256) void k_fillb(const int* __restrict__ src, int* __restrict__ cnt,
                                               int* __restrict__ order, int E) {
    int e = blockIdx.x * 256 + threadIdx.x;
    if (e < E) {
        int s = src[e];
        int p = atomicAdd(&cnt[s], 1);
        if (p < CAP) order[(size_t)s * CAP + p] = e;
    }
}

// ---------------- gather-mean: one wave per node (R6 proven form) ----------------
__global__ __launch_bounds__(256) void k_gather(const float* __restrict__ ea, const int* __restrict__ order,
                                                const int* __restrict__ cnt,
                                                unsigned short* __restrict__ ve, int n) {
    int node = blockIdx.x * 4 + (threadIdx.x >> 6);
    if (node >= n) return;
    int lane = threadIdx.x & 63;
    int c = cnt[node];
    if (c > CAP) c = CAP;
    size_t base = (size_t)node * CAP;

    int id0 = (lane < c) ? order[base + lane] : 0;
    int id1 = (c > 64 && lane < c - 64) ? order[base + 64 + lane] : 0;

    float s0 = 0.f, s1 = 0.f;
    f32x2 cur[8], nxt[8];

    int nb = c >> 3;
    if (nb > 0) {
#pragma unroll
        for (int k = 0; k < 8; ++k) {
            int eid = __shfl(id0, k, 64);
            cur[k] = __builtin_nontemporal_load(reinterpret_cast<const f32x2*>(ea + (size_t)eid * DIMF) + lane);
        }
        for (int b = 1; b < nb; ++b) {
            int j0 = b * 8;
#pragma unroll
            for (int k = 0; k < 8; ++k) {
                int j = j0 + k;
                int eid = (j < 64) ? __shfl(id0, j, 64) : __shfl(id1, j - 64, 64);
                nxt[k] = __builtin_nontemporal_load(reinterpret_cast<const f32x2*>(ea + (size_t)eid * DIMF) + lane);
            }
#pragma unroll
            for (int k = 0; k < 8; ++k) {
                s0 += cur[k][0]; s1 += cur[k][1];
                cur[k] = nxt[k];
            }
        }
#pragma unroll
        for (int k = 0; k < 8; ++k) { s0 += cur[k][0]; s1 += cur[k][1]; }
    }
    for (int j = nb * 8; j < c; ++j) {
        int eid = (j < 64) ? __shfl(id0, j, 64) : __shfl(id1, j - 64, 64);
        f32x2 v = __builtin_nontemporal_load(reinterpret_cast<const f32x2*>(ea + (size_t)eid * DIMF) + lane);
        s0 += v[0]; s1 += v[1];
    }

    float inv = 1.0f / (float)(c > 1 ? c : 1);
    ushort2 o = { f2bf(s0 * inv), f2bf(s1 * inv) };
    *reinterpret_cast<ushort2*>(ve + (size_t)node * DIMF + lane * 2) = o;
}

#define BM 128

// ---------------- GEMM layer 0: BM=128, 8 waves, 3 K-chunks (x | ve | u[batch]) ----------------
__global__ __launch_bounds__(512) void k_gemm0(const float* __restrict__ x,
                                               const unsigned short* __restrict__ ve,
                                               const float* __restrict__ u,
                                               const int* __restrict__ batch,
                                               const unsigned short* __restrict__ W,   // [128][384] bf16
                                               const float* __restrict__ bias,
                                               unsigned short* __restrict__ H,
                                               float* __restrict__ st, int rows) {
    __shared__ __align__(16) unsigned short lA[BM][136];
    __shared__ __align__(16) unsigned short lB[DIMF][136];
    __shared__ float sm[DIMF], sq[DIMF];
    __shared__ int sbatch[BM];
    int tid = threadIdx.x;
    int row0 = blockIdx.x * BM;
    if (tid < DIMF) { sm[tid] = 0.f; sq[tid] = 0.f; }
    if (tid < BM) {
        int gr = row0 + tid;
        sbatch[tid] = (gr < rows) ? batch[gr] : 0;
    }

    int lane = tid & 63, wave = tid >> 6;   // wave 0..7
    int wm = wave >> 1, wn = wave & 1;      // 4x2: 32-row strips x 64-col halves
    int l15 = lane & 15, l4 = lane >> 4;
    f32x4 acc[2][4] = {};

    int fr = tid >> 5, fc = (tid & 31) * 4;   // f32 map: 16 rows/iter
    int hr = tid >> 4, hc = (tid & 15) * 8;   // bf16 map: 32 rows/iter

#pragma unroll
    for (int chunk = 0; chunk < 3; ++chunk) {
        if (chunk == 0) {
#pragma unroll
            for (int i = 0; i < 8; ++i) {
                int r = fr + i * 16;
                int gr = row0 + r;
                float4 v = (gr < rows) ? *reinterpret_cast<const float4*>(x + (size_t)gr * DIMF + fc)
                                       : float4{0.f, 0.f, 0.f, 0.f};
                ushort4 o2 = { f2bf(v.x), f2bf(v.y), f2bf(v.z), f2bf(v.w) };
                *reinterpret_cast<ushort4*>(&lA[r][fc]) = o2;
            }
        } else if (chunk == 1) {
#pragma unroll
            for (int i = 0; i < 4; ++i) {
                int r = hr + i * 32;
                int gr = row0 + r;
                uint4 v = (gr < rows) ? *reinterpret_cast<const uint4*>(ve + (size_t)gr * DIMF + hc)
                                      : uint4{0u, 0u, 0u, 0u};
                *reinterpret_cast<uint4*>(&lA[r][hc]) = v;
            }
        } else {
#pragma unroll
            for (int i = 0; i < 8; ++i) {
                int r = fr + i * 16;
                int gr = row0 + r;
                int b = sbatch[r];
                float4 v = (gr < rows) ? *reinterpret_cast<const float4*>(u + (size_t)b * DIMF + fc)
                                       : float4{0.f, 0.f, 0.f, 0.f};
                ushort4 o2 = { f2bf(v.x), f2bf(v.y), f2bf(v.z), f2bf(v.w) };
                *reinterpret_cast<ushort4*>(&lA[r][fc]) = o2;
            }
        }
#pragma unroll
        for (int i = 0; i < 4; ++i) {
            int r = hr + i * 32;
            uint4 v = *reinterpret_cast<const uint4*>(W + (size_t)r * 384 + chunk * 128 + hc);
            *reinterpret_cast<uint4*>(&lB[r][hc]) = v;
        }
        __syncthreads();
#pragma unroll
        for (int ks = 0; ks < 4; ++ks) {
            bf16x8 af[2], bfr[4];
#pragma unroll
            for (int mi = 0; mi < 2; ++mi)
                af[mi] = *reinterpret_cast<const bf16x8*>(&lA[wm * 32 + mi * 16 + l15][ks * 32 + l4 * 8]);
#pragma unroll
            for (int ni = 0; ni < 4; ++ni)
                bfr[ni] = *reinterpret_cast<const bf16x8*>(&lB[wn * 64 + ni * 16 + l15][ks * 32 + l4 * 8]);
#pragma unroll
            for (int mi = 0; mi < 2; ++mi)
#pragma unroll
                for (int ni = 0; ni < 4; ++ni)
                    acc[mi][ni] = __builtin_amdgcn_mfma_f32_16x16x32_bf16(af[mi], bfr[ni], acc[mi][ni], 0, 0, 0);
        }
        __syncthreads();
    }

#pragma unroll
    for (int mi = 0; mi < 2; ++mi)
#pragma unroll
        for (int ni = 0; ni < 4; ++ni) {
            int c = wn * 64 + ni * 16 + l15;
            float s = 0.f, q = 0.f;
#pragma unroll
            for (int i = 0; i < 4; ++i) {
                int r = row0 + wm * 32 + mi * 16 + l4 * 4 + i;
                if (r < rows) {
                    float z = acc[mi][ni][i] + bias[c];
                    z = fmaxf(z, 0.f);
                    H[(size_t)r * DIMF + c] = f2bf(z);
                    s += z; q += z * z;
                }
            }
            atomicAdd(&sm[c], s);
            atomicAdd(&sq[c], q);
        }
    __syncthreads();
    if (tid < DIMF) { atomicAdd(&st[tid], sm[tid]); atomicAdd(&st[DIMF + tid], sq[tid]); }
}

// ---------------- GEMM layers 1,2: BM=128, 8 waves, in-kernel BN fold ----------------
__global__ __launch_bounds__(512) void k_gemmF(const unsigned short* __restrict__ A,
                                               const float* __restrict__ W,     // [128][128] fp32 (raw)
                                               const float* __restrict__ bn,    // raw bias
                                               const float* __restrict__ stp,   // prev-layer stats
                                               const float* __restrict__ g,
                                               const float* __restrict__ bt,
                                               unsigned short* __restrict__ H,
                                               float* __restrict__ st, int rows) {
    const int K = 128;
    __shared__ __align__(16) unsigned short lA[BM][136];
    __shared__ __align__(16) unsigned short lB[DIMF][136];
    __shared__ float sS[DIMF], sT[DIMF], bb[DIMF], sm[DIMF], sq[DIMF];
    int tid = threadIdx.x;
    int row0 = blockIdx.x * BM;

    if (tid < DIMF) {
        float invn = 1.0f / (float)rows;
        float mu = stp[tid] * invn;
        float var = stp[DIMF + tid] * invn - mu * mu;
        var = var > 0.f ? var : 0.f;
        float sc = rsqrtf(var + 1e-5f) * g[tid];
        sS[tid] = sc;
        sT[tid] = bt[tid] - mu * sc;
        sm[tid] = 0.f; sq[tid] = 0.f;
    }

    int hr = tid >> 4, hc = (tid & 15) * 8;
#pragma unroll
    for (int i = 0; i < 4; ++i) {
        int r = hr + i * 32;
        int gr = row0 + r;
        uint4 v = (gr < rows) ? *reinterpret_cast<const uint4*>(A + (size_t)gr * K + hc)
                              : uint4{0u, 0u, 0u, 0u};
        *reinterpret_cast<uint4*>(&lA[r][hc]) = v;
    }
    __syncthreads();   // sS/sT ready, lA ready

    int fr = tid >> 5, fc = (tid & 31) * 4;
#pragma unroll
    for (int it = 0; it < 8; ++it) {
        int r = fr + it * 16;
        float4 w = *reinterpret_cast<const float4*>(W + (size_t)r * K + fc);
        ushort4 ob = { f2bf(w.x * sS[fc]), f2bf(w.y * sS[fc + 1]),
                       f2bf(w.z * sS[fc + 2]), f2bf(w.w * sS[fc + 3]) };
        *reinterpret_cast<ushort4*>(&lB[r][fc]) = ob;
        float p = w.x * sT[fc] + w.y * sT[fc + 1] + w.z * sT[fc + 2] + w.w * sT[fc + 3];
#pragma unroll
        for (int m = 16; m > 0; m >>= 1) p += __shfl_xor(p, m, 32);
        if ((tid & 31) == 0) bb[r] = bn[r] + p;
    }
    __syncthreads();

    int lane = tid & 63, wave = tid >> 6;
    int wm = wave >> 1, wn = wave & 1;
    int l15 = lane & 15, l4 = lane >> 4;
    f32x4 acc[2][4] = {};

#pragma unroll
    for (int ks = 0; ks < 4; ++ks) {
        bf16x8 af[2], bfr[4];
#pragma unroll
        for (int mi = 0; mi < 2; ++mi)
            af[mi] = *reinterpret_cast<const bf16x8*>(&lA[wm * 32 + mi * 16 + l15][ks * 32 + l4 * 8]);
#pragma unroll
        for (int ni = 0; ni < 4; ++ni)
            bfr[ni] = *reinterpret_cast<const bf16x8*>(&lB[wn * 64 + ni * 16 + l15][ks * 32 + l4 * 8]);
#pragma unroll
        for (int mi = 0; mi < 2; ++mi)
#pragma unroll
            for (int ni = 0; ni < 4; ++ni)
                acc[mi][ni] = __builtin_amdgcn_mfma_f32_16x16x32_bf16(af[mi], bfr[ni], acc[mi][ni], 0, 0, 0);
    }

#pragma unroll
    for (int mi = 0; mi < 2; ++mi)
#pragma unroll
        for (int ni = 0; ni < 4; ++ni) {
            int c = wn * 64 + ni * 16 + l15;
            float s = 0.f, q = 0.f;
#pragma unroll
            for (int i = 0; i < 4; ++i) {
                int r = row0 + wm * 32 + mi * 16 + l4 * 4 + i;
                if (r < rows) {
                    float z = acc[mi][ni][i] + bb[c];
                    z = fmaxf(z, 0.f);
                    H[(size_t)r * DIMF + c] = f2bf(z);
                    s += z; q += z * z;
                }
            }
            atomicAdd(&sm[c], s);
            atomicAdd(&sq[c], q);
        }
    __syncthreads();
    if (tid < DIMF) { atomicAdd(&st[tid], sm[tid]); atomicAdd(&st[DIMF + tid], sq[tid]); }
}

// final: out = h2 * s + t, BN params computed inline from st
__global__ __launch_bounds__(256) void k_final(const unsigned short* __restrict__ H, const float* __restrict__ st,
                                               const float* __restrict__ g, const float* __restrict__ bt,
                                               float* __restrict__ out, int n) {
    int idx = blockIdx.x * 256 + threadIdx.x;
    if (idx >= n * 32) return;
    int r = idx >> 5, q = (idx & 31) * 4;
    float invn = 1.0f / (float)n;
    ushort4 h = *reinterpret_cast<const ushort4*>(H + (size_t)r * DIMF + q);
    float hv[4] = { bf2f(h.x), bf2f(h.y), bf2f(h.z), bf2f(h.w) };
    float ov[4];
#pragma unroll
    for (int k = 0; k < 4; ++k) {
        int c = q + k;
        float mu = st[c] * invn;
        float var = st[DIMF + c] * invn - mu * mu;
        var = var > 0.f ? var : 0.f;
        float sc = rsqrtf(var + 1e-5f) * g[c];
        ov[k] = hv[k] * sc + (bt[c] - mu * sc);
    }
    float4 o = { ov[0], ov[1], ov[2], ov[3] };
    *reinterpret_cast<float4*>(out + (size_t)r * DIMF + q) = o;
}

extern "C" void kernel_launch(void* const* d_in, const int* in_sizes, int n_in,
                              void* d_out, int out_size, void* d_ws, size_t ws_size,
                              hipStream_t stream) {
    const float* x   = (const float*)d_in[0];
    const float* ea  = (const float*)d_in[1];
    const float* u   = (const float*)d_in[2];
    const int* eidx  = (const int*)d_in[3];
    const int* batch = (const int*)d_in[4];
    const float* W0  = (const float*)d_in[5];
    const float* b0  = (const float*)d_in[6];
    const float* W1  = (const float*)d_in[7];
    const float* b1  = (const float*)d_in[8];
    const float* W2  = (const float*)d_in[9];
    const float* b2  = (const float*)d_in[10];
    const float* g0  = (const float*)d_in[11];
    const float* bt0 = (const float*)d_in[12];
    const float* g1  = (const float*)d_in[13];
    const float* bt1 = (const float*)d_in[14];
    const float* g2  = (const float*)d_in[15];
    const float* bt2 = (const float*)d_in[16];

    int N = in_sizes[0] / DIMF;
    int E = in_sizes[1] / DIMF;
    const int* src = eidx;  // row 0 of edge_index

    char* base = (char*)d_ws;
    size_t o = 0;
    auto alloc = [&](size_t sz) { size_t p = o; o = (o + sz + 255) & ~(size_t)255; return p; };
    size_t off_cnt   = alloc((size_t)N * 4);          // zeroed by k_zero_wconv
    size_t off_st    = alloc(3 * 256 * 4);            // zeroed (contiguous with cnt)
    size_t off_order = alloc((size_t)N * CAP * 4);
    size_t off_W0b   = alloc((size_t)DIMF * 384 * 2);
    size_t off_ve    = alloc((size_t)N * DIMF * 2);
    size_t off_h0    = alloc((size_t)N * DIMF * 2);
    size_t off_h1    = alloc((size_t)N * DIMF * 2);
    size_t off_h2    = alloc((size_t)N * DIMF * 2);

    int* cnt        = (int*)(base + off_cnt);
    float* st       = (float*)(base + off_st);
    int* order      = (int*)(base + off_order);
    unsigned short* W0b = (unsigned short*)(base + off_W0b);
    unsigned short* ve  = (unsigned short*)(base + off_ve);
    unsigned short* h0  = (unsigned short*)(base + off_h0);
    unsigned short* h1  = (unsigned short*)(base + off_h1);
    unsigned short* h2  = (unsigned short*)(base + off_h2);
    float* outp = (float*)d_out;

    int zints = (int)((off_st + 3 * 256 * 4) / 4);   // cnt + st contiguous zero region
    int EB = (E + 255) / 256;
    int NQ = (N * 32 + 255) / 256;
    int GB = (N + BM - 1) / BM;
    int GG = (N + 3) / 4;

    k_zero_wconv<<<256, 256, 0, stream>>>((int*)base, zints, W0, W0b, DIMF * 384 / 4);
    k_fillb<<<EB, 256, 0, stream>>>(src, cnt, order, E);
    k_gather<<<GG, 256, 0, stream>>>(ea, order, cnt, ve, N);

    // layer 0 (stats fused)
    k_gemm0<<<GB, 512, 0, stream>>>(x, ve, u, batch, W0b, b0, h0, st, N);
    // layer 1 (BN0 folded in-kernel, stats fused)
    k_gemmF<<<GB, 512, 0, stream>>>(h0, W1, b1, st, g0, bt0, h1, st + 256, N);
    // layer 2 (BN1 folded in-kernel, stats fused)
    k_gemmF<<<GB, 512, 0, stream>>>(h1, W2, b2, st + 256, g1, bt1, h2, st + 512, N);
    // final BN2
    k_final<<<NQ, 256, 0, stream>>>(h2, st + 512, g2, bt2, outp, N);
}

// Round 12
// 516.186 us; speedup vs baseline: 4.4533x; 1.0297x over previous
//
#include <hip/hip_runtime.h>

#define DIMF 128
#define CAP 128   // max edges per node bucket (deg ~ Poisson(16), max ~45 over 100K nodes)

typedef __bf16 bf16x8 __attribute__((ext_vector_type(8)));
typedef float f32x4 __attribute__((ext_vector_type(4)));
typedef float f32x2 __attribute__((ext_vector_type(2)));

__device__ __forceinline__ unsigned short f2bf(float f) {
    union { float f; unsigned u; } v; v.f = f;
    unsigned r = v.u + 0x7FFFu + ((v.u >> 16) & 1u);
    return (unsigned short)(r >> 16);
}
__device__ __forceinline__ float bf2f(unsigned short h) {
    union { unsigned u; float f; } v; v.u = ((unsigned)h) << 16; return v.f;
}

// ---------------- fused: zero cnt+st, convert W0 -> bf16 ----------------
__global__ __launch_bounds__(256) void k_zero_wconv(int* __restrict__ zbase, int zints,
                                                    const float* __restrict__ W, unsigned short* __restrict__ Wb,
                                                    int n4) {
    int idx = blockIdx.x * 256 + threadIdx.x;
    int z0 = idx * 2;
    if (z0 + 1 < zints) {
        *reinterpret_cast<int2*>(zbase + z0) = int2{0, 0};
    } else if (z0 < zints) {
        zbase[z0] = 0;
    }
    if (idx < n4) {
        float4 v = *reinterpret_cast<const float4*>(W + (size_t)idx * 4);
        ushort4 o = { f2bf(v.x), f2bf(v.y), f2bf(v.z), f2bf(v.w) };
        *reinterpret_cast<ushort4*>(Wb + (size_t)idx * 4) = o;
    }
}

// ---------------- single-pass bucketed edge binning ----------------
__global__ __launch_bounds__(256) void k_fillb(const int* __restrict__ src, int* __restrict__ cnt,
                                               int* __restrict__ order, int E) {
    int e = blockIdx.x * 256 + threadIdx.x;
    if (e < E) {
        int s = src[e];
        int p = atomicAdd(&cnt[s], 1);
        if (p < CAP) order[(size_t)s * CAP + p] = e;
    }
}

// ---------------- gather-mean: one wave per node, half-wave row split ----------------
// lanes 0-31 even rows, lanes 32-63 odd rows; float4/lane -> 1KB (2 rows)/instr.
// ALL loop bounds are wave-uniform (mu); only the accumulate is predicated
// (t < m) -- __shfl never executes divergent (CDNA bpermute reads from
// inactive lanes are undefined; this was R11's bug).
__global__ __launch_bounds__(256) void k_gather(const float* __restrict__ ea, const int* __restrict__ order,
                                                const int* __restrict__ cnt,
                                                unsigned short* __restrict__ ve, int n) {
    int node = blockIdx.x * 4 + (threadIdx.x >> 6);
    if (node >= n) return;
    int lane = threadIdx.x & 63;
    int half = lane >> 5;
    int l32 = lane & 31;
    int c = cnt[node];
    if (c > CAP) c = CAP;
    size_t base = (size_t)node * CAP;

    int id0 = (lane < c) ? order[base + lane] : 0;
    int id1 = (c > 64 && lane < c - 64) ? order[base + 64 + lane] : 0;

    int m  = (c > half) ? ((c - half + 1) >> 1) : 0;  // valid rows for this half
    int mu = (c + 1) >> 1;                             // uniform trip count (max of halves)

#define EID(t) ({ int j_ = half + 2 * (t); \
                  (j_ < 64) ? __shfl(id0, j_, 64) : __shfl(id1, j_ - 64, 64); })
#define LDR(eid) __builtin_nontemporal_load(reinterpret_cast<const f32x4*>(ea + (size_t)(eid) * DIMF) + l32)

    f32x4 s = {0.f, 0.f, 0.f, 0.f};
    f32x4 cur[4], nxt[4];
    int tb = mu >> 2;
    if (tb > 0) {
#pragma unroll
        for (int k = 0; k < 4; ++k) cur[k] = LDR(EID(k));
        for (int b = 1; b < tb; ++b) {
#pragma unroll
            for (int k = 0; k < 4; ++k) nxt[k] = LDR(EID(b * 4 + k));
#pragma unroll
            for (int k = 0; k < 4; ++k) {
                int t = (b - 1) * 4 + k;
                if (t < m) s += cur[k];
                cur[k] = nxt[k];
            }
        }
#pragma unroll
        for (int k = 0; k < 4; ++k) {
            int t = (tb - 1) * 4 + k;
            if (t < m) s += cur[k];
        }
    }
    for (int t = tb * 4; t < mu; ++t) {
        f32x4 v = LDR(EID(t));
        if (t < m) s += v;
    }
#undef EID
#undef LDR

    // combine halves (both cover cols l32*4..+3)
    s[0] += __shfl_xor(s[0], 32, 64);
    s[1] += __shfl_xor(s[1], 32, 64);
    s[2] += __shfl_xor(s[2], 32, 64);
    s[3] += __shfl_xor(s[3], 32, 64);

    if (lane < 32) {
        float inv = 1.0f / (float)(c > 1 ? c : 1);
        ushort4 o = { f2bf(s[0] * inv), f2bf(s[1] * inv), f2bf(s[2] * inv), f2bf(s[3] * inv) };
        *reinterpret_cast<ushort4*>(ve + (size_t)node * DIMF + l32 * 4) = o;
    }
}

#define BM 128

// ---------------- GEMM layer 0: BM=128, 8 waves, 3 K-chunks (x | ve | u[batch]) ----------------
__global__ __launch_bounds__(512) void k_gemm0(const float* __restrict__ x,
                                               const unsigned short* __restrict__ ve,
                                               const float* __restrict__ u,
                                               const int* __restrict__ batch,
                                               const unsigned short* __restrict__ W,   // [128][384] bf16
                                               const float* __restrict__ bias,
                                               unsigned short* __restrict__ H,
                                               float* __restrict__ st, int rows) {
    __shared__ __align__(16) unsigned short lA[BM][136];
    __shared__ __align__(16) unsigned short lB[DIMF][136];
    __shared__ float sm[DIMF], sq[DIMF];
    __shared__ int sbatch[BM];
    int tid = threadIdx.x;
    int row0 = blockIdx.x * BM;
    if (tid < DIMF) { sm[tid] = 0.f; sq[tid] = 0.f; }
    if (tid < BM) {
        int gr = row0 + tid;
        sbatch[tid] = (gr < rows) ? batch[gr] : 0;
    }

    int lane = tid & 63, wave = tid >> 6;   // wave 0..7
    int wm = wave >> 1, wn = wave & 1;      // 4x2: 32-row strips x 64-col halves
    int l15 = lane & 15, l4 = lane >> 4;
    f32x4 acc[2][4] = {};

    int fr = tid >> 5, fc = (tid & 31) * 4;   // f32 map: 16 rows/iter
    int hr = tid >> 4, hc = (tid & 15) * 8;   // bf16 map: 32 rows/iter

#pragma unroll
    for (int chunk = 0; chunk < 3; ++chunk) {
        if (chunk == 0) {
#pragma unroll
            for (int i = 0; i < 8; ++i) {
                int r = fr + i * 16;
                int gr = row0 + r;
                float4 v = (gr < rows) ? *reinterpret_cast<const float4*>(x + (size_t)gr * DIMF + fc)
                                       : float4{0.f, 0.f, 0.f, 0.f};
                ushort4 o2 = { f2bf(v.x), f2bf(v.y), f2bf(v.z), f2bf(v.w) };
                *reinterpret_cast<ushort4*>(&lA[r][fc]) = o2;
            }
        } else if (chunk == 1) {
#pragma unroll
            for (int i = 0; i < 4; ++i) {
                int r = hr + i * 32;
                int gr = row0 + r;
                uint4 v = (gr < rows) ? *reinterpret_cast<const uint4*>(ve + (size_t)gr * DIMF + hc)
                                      : uint4{0u, 0u, 0u, 0u};
                *reinterpret_cast<uint4*>(&lA[r][hc]) = v;
            }
        } else {
#pragma unroll
            for (int i = 0; i < 8; ++i) {
                int r = fr + i * 16;
                int gr = row0 + r;
                int b = sbatch[r];
                float4 v = (gr < rows) ? *reinterpret_cast<const float4*>(u + (size_t)b * DIMF + fc)
                                       : float4{0.f, 0.f, 0.f, 0.f};
                ushort4 o2 = { f2bf(v.x), f2bf(v.y), f2bf(v.z), f2bf(v.w) };
                *reinterpret_cast<ushort4*>(&lA[r][fc]) = o2;
            }
        }
#pragma unroll
        for (int i = 0; i < 4; ++i) {
            int r = hr + i * 32;
            uint4 v = *reinterpret_cast<const uint4*>(W + (size_t)r * 384 + chunk * 128 + hc);
            *reinterpret_cast<uint4*>(&lB[r][hc]) = v;
        }
        __syncthreads();
#pragma unroll
        for (int ks = 0; ks < 4; ++ks) {
            bf16x8 af[2], bfr[4];
#pragma unroll
            for (int mi = 0; mi < 2; ++mi)
                af[mi] = *reinterpret_cast<const bf16x8*>(&lA[wm * 32 + mi * 16 + l15][ks * 32 + l4 * 8]);
#pragma unroll
            for (int ni = 0; ni < 4; ++ni)
                bfr[ni] = *reinterpret_cast<const bf16x8*>(&lB[wn * 64 + ni * 16 + l15][ks * 32 + l4 * 8]);
#pragma unroll
            for (int mi = 0; mi < 2; ++mi)
#pragma unroll
                for (int ni = 0; ni < 4; ++ni)
                    acc[mi][ni] = __builtin_amdgcn_mfma_f32_16x16x32_bf16(af[mi], bfr[ni], acc[mi][ni], 0, 0, 0);
        }
        __syncthreads();
    }

#pragma unroll
    for (int mi = 0; mi < 2; ++mi)
#pragma unroll
        for (int ni = 0; ni < 4; ++ni) {
            int c = wn * 64 + ni * 16 + l15;
            float s = 0.f, q = 0.f;
#pragma unroll
            for (int i = 0; i < 4; ++i) {
                int r = row0 + wm * 32 + mi * 16 + l4 * 4 + i;
                if (r < rows) {
                    float z = acc[mi][ni][i] + bias[c];
                    z = fmaxf(z, 0.f);
                    H[(size_t)r * DIMF + c] = f2bf(z);
                    s += z; q += z * z;
                }
            }
            atomicAdd(&sm[c], s);
            atomicAdd(&sq[c], q);
        }
    __syncthreads();
    if (tid < DIMF) { atomicAdd(&st[tid], sm[tid]); atomicAdd(&st[DIMF + tid], sq[tid]); }
}

// ---------------- GEMM layers 1,2: BM=128, 8 waves, in-kernel BN fold ----------------
__global__ __launch_bounds__(512) void k_gemmF(const unsigned short* __restrict__ A,
                                               const float* __restrict__ W,     // [128][128] fp32 (raw)
                                               const float* __restrict__ bn,    // raw bias
                                               const float* __restrict__ stp,   // prev-layer stats
                                               const float* __restrict__ g,
                                               const float* __restrict__ bt,
                                               unsigned short* __restrict__ H,
                                               float* __restrict__ st, int rows) {
    const int K = 128;
    __shared__ __align__(16) unsigned short lA[BM][136];
    __shared__ __align__(16) unsigned short lB[DIMF][136];
    __shared__ float sS[DIMF], sT[DIMF], bb[DIMF], sm[DIMF], sq[DIMF];
    int tid = threadIdx.x;
    int row0 = blockIdx.x * BM;

    if (tid < DIMF) {
        float invn = 1.0f / (float)rows;
        float mu = stp[tid] * invn;
        float var = stp[DIMF + tid] * invn - mu * mu;
        var = var > 0.f ? var : 0.f;
        float sc = rsqrtf(var + 1e-5f) * g[tid];
        sS[tid] = sc;
        sT[tid] = bt[tid] - mu * sc;
        sm[tid] = 0.f; sq[tid] = 0.f;
    }

    int hr = tid >> 4, hc = (tid & 15) * 8;
#pragma unroll
    for (int i = 0; i < 4; ++i) {
        int r = hr + i * 32;
        int gr = row0 + r;
        uint4 v = (gr < rows) ? *reinterpret_cast<const uint4*>(A + (size_t)gr * K + hc)
                              : uint4{0u, 0u, 0u, 0u};
        *reinterpret_cast<uint4*>(&lA[r][hc]) = v;
    }
    __syncthreads();   // sS/sT ready, lA ready

    int fr = tid >> 5, fc = (tid & 31) * 4;
#pragma unroll
    for (int it = 0; it < 8; ++it) {
        int r = fr + it * 16;
        float4 w = *reinterpret_cast<const float4*>(W + (size_t)r * K + fc);
        ushort4 ob = { f2bf(w.x * sS[fc]), f2bf(w.y * sS[fc + 1]),
                       f2bf(w.z * sS[fc + 2]), f2bf(w.w * sS[fc + 3]) };
        *reinterpret_cast<ushort4*>(&lB[r][fc]) = ob;
        float p = w.x * sT[fc] + w.y * sT[fc + 1] + w.z * sT[fc + 2] + w.w * sT[fc + 3];
#pragma unroll
        for (int m = 16; m > 0; m >>= 1) p += __shfl_xor(p, m, 32);
        if ((tid & 31) == 0) bb[r] = bn[r] + p;
    }
    __syncthreads();

    int lane = tid & 63, wave = tid >> 6;
    int wm = wave >> 1, wn = wave & 1;
    int l15 = lane & 15, l4 = lane >> 4;
    f32x4 acc[2][4] = {};

#pragma unroll
    for (int ks = 0; ks < 4; ++ks) {
        bf16x8 af[2], bfr[4];
#pragma unroll
        for (int mi = 0; mi < 2; ++mi)
            af[mi] = *reinterpret_cast<const bf16x8*>(&lA[wm * 32 + mi * 16 + l15][ks * 32 + l4 * 8]);
#pragma unroll
        for (int ni = 0; ni < 4; ++ni)
            bfr[ni] = *reinterpret_cast<const bf16x8*>(&lB[wn * 64 + ni * 16 + l15][ks * 32 + l4 * 8]);
#pragma unroll
        for (int mi = 0; mi < 2; ++mi)
#pragma unroll
            for (int ni = 0; ni < 4; ++ni)
                acc[mi][ni] = __builtin_amdgcn_mfma_f32_16x16x32_bf16(af[mi], bfr[ni], acc[mi][ni], 0, 0, 0);
    }

#pragma unroll
    for (int mi = 0; mi < 2; ++mi)
#pragma unroll
        for (int ni = 0; ni < 4; ++ni) {
            int c = wn * 64 + ni * 16 + l15;
            float s = 0.f, q = 0.f;
#pragma unroll
            for (int i = 0; i < 4; ++i) {
                int r = row0 + wm * 32 + mi * 16 + l4 * 4 + i;
                if (r < rows) {
                    float z = acc[mi][ni][i] + bb[c];
                    z = fmaxf(z, 0.f);
                    H[(size_t)r * DIMF + c] = f2bf(z);
                    s += z; q += z * z;
                }
            }
            atomicAdd(&sm[c], s);
            atomicAdd(&sq[c], q);
        }
    __syncthreads();
    if (tid < DIMF) { atomicAdd(&st[tid], sm[tid]); atomicAdd(&st[DIMF + tid], sq[tid]); }
}

// final: out = h2 * s + t, BN params computed inline from st
__global__ __launch_bounds__(256) void k_final(const unsigned short* __restrict__ H, const float* __restrict__ st,
                                               const float* __restrict__ g, const float* __restrict__ bt,
                                               float* __restrict__ out, int n) {
    int idx = blockIdx.x * 256 + threadIdx.x;
    if (idx >= n * 32) return;
    int r = idx >> 5, q = (idx & 31) * 4;
    float invn = 1.0f / (float)n;
    ushort4 h = *reinterpret_cast<const ushort4*>(H + (size_t)r * DIMF + q);
    float hv[4] = { bf2f(h.x), bf2f(h.y), bf2f(h.z), bf2f(h.w) };
    float ov[4];
#pragma unroll
    for (int k = 0; k < 4; ++k) {
        int c = q + k;
        float mu = st[c] * invn;
        float var = st[DIMF + c] * invn - mu * mu;
        var = var > 0.f ? var : 0.f;
        float sc = rsqrtf(var + 1e-5f) * g[c];
        ov[k] = hv[k] * sc + (bt[c] - mu * sc);
    }
    float4 o = { ov[0], ov[1], ov[2], ov[3] };
    *reinterpret_cast<float4*>(out + (size_t)r * DIMF + q) = o;
}

extern "C" void kernel_launch(void* const* d_in, const int* in_sizes, int n_in,
                              void* d_out, int out_size, void* d_ws, size_t ws_size,
                              hipStream_t stream) {
    const float* x   = (const float*)d_in[0];
    const float* ea  = (const float*)d_in[1];
    const float* u   = (const float*)d_in[2];
    const int* eidx  = (const int*)d_in[3];
    const int* batch = (const int*)d_in[4];
    const float* W0  = (const float*)d_in[5];
    const float* b0  = (const float*)d_in[6];
    const float* W1  = (const float*)d_in[7];
    const float* b1  = (const float*)d_in[8];
    const float* W2  = (const float*)d_in[9];
    const float* b2  = (const float*)d_in[10];
    const float* g0  = (const float*)d_in[11];
    const float* bt0 = (const float*)d_in[12];
    const float* g1  = (const float*)d_in[13];
    const float* bt1 = (const float*)d_in[14];
    const float* g2  = (const float*)d_in[15];
    const float* bt2 = (const float*)d_in[16];

    int N = in_sizes[0] / DIMF;
    int E = in_sizes[1] / DIMF;
    const int* src = eidx;  // row 0 of edge_index

    char* base = (char*)d_ws;
    size_t o = 0;
    auto alloc = [&](size_t sz) { size_t p = o; o = (o + sz + 255) & ~(size_t)255; return p; };
    size_t off_cnt   = alloc((size_t)N * 4);          // zeroed by k_zero_wconv
    size_t off_st    = alloc(3 * 256 * 4);            // zeroed (contiguous with cnt)
    size_t off_order = alloc((size_t)N * CAP * 4);
    size_t off_W0b   = alloc((size_t)DIMF * 384 * 2);
    size_t off_ve    = alloc((size_t)N * DIMF * 2);
    size_t off_h0    = alloc((size_t)N * DIMF * 2);
    size_t off_h1    = alloc((size_t)N * DIMF * 2);
    size_t off_h2    = alloc((size_t)N * DIMF * 2);

    int* cnt        = (int*)(base + off_cnt);
    float* st       = (float*)(base + off_st);
    int* order      = (int*)(base + off_order);
    unsigned short* W0b = (unsigned short*)(base + off_W0b);
    unsigned short* ve  = (unsigned short*)(base + off_ve);
    unsigned short* h0  = (unsigned short*)(base + off_h0);
    unsigned short* h1  = (unsigned short*)(base + off_h1);
    unsigned short* h2  = (unsigned short*)(base + off_h2);
    float* outp = (float*)d_out;

    int zints = (int)((off_st + 3 * 256 * 4) / 4);   // cnt + st contiguous zero region
    int EB = (E + 255) / 256;
    int NQ = (N * 32 + 255) / 256;
    int GB = (N + BM - 1) / BM;
    int GG = (N + 3) / 4;

    k_zero_wconv<<<256, 256, 0, stream>>>((int*)base, zints, W0, W0b, DIMF * 384 / 4);
    k_fillb<<<EB, 256, 0, stream>>>(src, cnt, order, E);
    k_gather<<<GG, 256, 0, stream>>>(ea, order, cnt, ve, N);

    // layer 0 (stats fused)
    k_gemm0<<<GB, 512, 0, stream>>>(x, ve, u, batch, W0b, b0, h0, st, N);
    // layer 1 (BN0 folded in-kernel, stats fused)
    k_gemmF<<<GB, 512, 0, stream>>>(h0, W1, b1, st, g0, bt0, h1, st + 256, N);
    // layer 2 (BN1 folded in-kernel, stats fused)
    k_gemmF<<<GB, 512, 0, stream>>>(h1, W2, b2, st + 256, g1, bt1, h2, st + 512, N);
    // final BN2
    k_final<<<NQ, 256, 0, stream>>>(h2, st + 512, g2, bt2, outp, N);
}